// Round 18
// baseline (768.008 us; speedup 1.0000x reference)
//
#include <hip/hip_runtime.h>
#include <hip/hip_bf16.h>

#define NWIN   4096
#define NTOK   49
#define CDIM   384
#define NHEAD  12
#define QKVN   1152
#define SLICE  1568            // 49*32 elems per (win,head,tensor) slice
#define MPROW  28              // packed-mask row stride (u32), 112B

typedef __attribute__((ext_vector_type(8))) short bf16x8;
typedef __attribute__((ext_vector_type(4))) short bf16x4;
typedef __attribute__((ext_vector_type(4))) float f32x4;
typedef __attribute__((ext_vector_type(2))) unsigned int u32x2;
typedef unsigned int u32;
typedef unsigned short u16;

static __device__ __forceinline__ u16 f2bf(float f) {
  union { float f; u32 u; } w; w.f = f;
  u32 r = w.u + 0x7fffu + ((w.u >> 16) & 1u);
  return (u16)(r >> 16);
}
static __device__ __forceinline__ float blo(u32 v) {
  union { u32 u; float f; } w; w.u = v << 16; return w.f;
}
static __device__ __forceinline__ float bhi(u32 v) {
  union { u32 u; float f; } w; w.u = v & 0xffff0000u; return w.f;
}
static __device__ __forceinline__ u32 cvtpk2(float lo, float hi) {
  u32 r; asm("v_cvt_pk_bf16_f32 %0, %1, %2" : "=v"(r) : "v"(lo), "v"(hi));
  return r;
}
static __device__ __forceinline__ void gld_lds16(const u16* g, u16* l) {
  __builtin_amdgcn_global_load_lds((const __attribute__((address_space(1))) u32*)g,
                                   (__attribute__((address_space(3))) u32*)l, 16, 0, 0);
}

// ---- prep: weights -> bf16, packed rel_bias gather, packed bf16 mask ----
__global__ void k_prep(const float* __restrict__ qkv_w, const float* __restrict__ proj_w,
                       const float* __restrict__ btab, const int* __restrict__ ridx,
                       const float* __restrict__ mask,
                       u16* __restrict__ wq, u16* __restrict__ wp, u32* __restrict__ rbp,
                       u32* __restrict__ mpk)
{
  const int n1 = QKVN * CDIM;
  const int n2 = CDIM * CDIM;
  const int n3 = NHEAD * NTOK * 26;
  const int n4 = NWIN * NTOK * MPROW;
  for (int i = blockIdx.x * blockDim.x + threadIdx.x; i < n1 + n2 + n3 + n4;
       i += gridDim.x * blockDim.x) {
    if (i < n1) {
      wq[i] = f2bf(qkv_w[i]);
    } else if (i < n1 + n2) {
      wp[i - n1] = f2bf(proj_w[i - n1]);
    } else if (i < n1 + n2 + n3) {
      int t = i - n1 - n2;
      int h = t / (NTOK * 26); int rem = t % (NTOK * 26);
      int r = rem / 26, p = rem % 26;
      float lo = 0.f, hi = 0.f;
      if (p < 25) {
        lo = btab[ridx[r * NTOK + 2 * p] * NHEAD + h];
        if (2 * p + 1 < NTOK) hi = btab[ridx[r * NTOK + 2 * p + 1] * NHEAD + h];
      }
      rbp[(h * NTOK + r) * 26 + p] = (u32)f2bf(lo) | ((u32)f2bf(hi) << 16);
    } else {
      int t2 = i - n1 - n2 - n3;          // [0, NWIN*49*28)
      int wi = t2 / MPROW, p = t2 - wi * MPROW;
      u32 v = 0;
      if (p < 25) {
        const float* mrow = mask + (long)wi * NTOK;   // wi = win*49 + row
        float lo = mrow[2 * p];
        float hi = (2 * p + 1 < NTOK) ? mrow[2 * p + 1] : 0.f;
        v = (u32)f2bf(lo) | ((u32)f2bf(hi) << 16);
      }
      mpk[t2] = v;
    }
  }
}

// ---------------- x fp32 -> bf16 ----------------
__global__ void k_convx(const float* __restrict__ x, u16* __restrict__ xb, long n8)
{
  long i = (long)blockIdx.x * blockDim.x + threadIdx.x;
  long stride = (long)gridDim.x * blockDim.x;
  for (; i < n8; i += stride) {
    const float4* p = (const float4*)x + i * 2;
    float4 a = p[0], b = p[1];
    u32 w0 = (u32)f2bf(a.x) | ((u32)f2bf(a.y) << 16);
    u32 w1 = (u32)f2bf(a.z) | ((u32)f2bf(a.w) << 16);
    u32 w2 = (u32)f2bf(b.x) | ((u32)f2bf(b.y) << 16);
    u32 w3 = (u32)f2bf(b.z) | ((u32)f2bf(b.w) << 16);
    uint4 v; v.x = w0; v.y = w1; v.z = w2; v.w = w3;
    ((uint4*)xb)[i] = v;
  }
}

// ---- 128x128 GEMM, T2 swizzle + XCD chunking + COUNTED-VMCNT double buffer:
//      stage(t+1) -> s_waitcnt vmcnt(8) (t's loads done, t+1's stay in flight)
//      -> raw s_barrier -> compute(t) -> raw s_barrier. No vmcnt(0) drain in
//      the main loop (T4; r10's dbuf failed because __syncthreads drains). ----
template<bool OUT_SLICE>
__global__ __launch_bounds__(256, 2)
void k_gemm(const u16* __restrict__ A, int lda,
            const u16* __restrict__ Bt, const float* __restrict__ bias,
            void* __restrict__ C, int ldc, int K, int tiles_n)
{
  __shared__ alignas(16) u16 As[2][128 * 64];
  __shared__ alignas(16) u16 Bs[2][128 * 64];
  const int tid = threadIdx.x;
  const int w = tid >> 6, l = tid & 63;

  // bijective XCD-chunk swizzle (m204)
  const int nwg = (int)gridDim.x;
  const int xcd = (int)blockIdx.x & 7, idx8 = (int)blockIdx.x >> 3;
  const int q8 = nwg >> 3, r8w = nwg & 7;
  const int lid = (xcd < r8w ? xcd * (q8 + 1) : r8w * (q8 + 1) + (xcd - r8w) * q8) + idx8;

  const int tm = lid / tiles_n, tn = lid % tiles_n;
  const int wm = (w >> 1) * 64, wn = (w & 1) * 64;
  const long arow0 = (long)tm * 128;
  const long brow0 = (long)tn * 128;
  const int r8 = l >> 3;                      // row within 8-row staging chunk
  const int c8 = ((l & 7) ^ r8) * 8;          // PRE-SWIZZLED source col (elems)

  auto stage = [&](int kk, int buf) {
#pragma unroll
    for (int q = 0; q < 4; ++q) {
      int ra = w * 32 + q * 8;
      gld_lds16(A  + (arow0 + ra + r8) * (long)lda + kk + c8, &As[buf][ra * 64]);
      gld_lds16(Bt + (brow0 + ra + r8) * (long)K   + kk + c8, &Bs[buf][ra * 64]);
    }
  };

  f32x4 acc[4][4];
  const f32x4 z = {0.f, 0.f, 0.f, 0.f};
#pragma unroll
  for (int m = 0; m < 4; ++m)
#pragma unroll
    for (int n = 0; n < 4; ++n) acc[m][n] = z;

  stage(0, 0);                               // outstanding = 8
  int cur = 0;
  for (int kk = 0; kk < K; kk += 64) {
    if (kk + 64 < K) {
      stage(kk + 64, cur ^ 1);               // outstanding = 16
      asm volatile("s_waitcnt vmcnt(8)" ::: "memory");   // kk's 8 landed
    } else {
      asm volatile("s_waitcnt vmcnt(0)" ::: "memory");
    }
    __builtin_amdgcn_sched_barrier(0);
    __builtin_amdgcn_s_barrier();            // raw: no vmcnt(0) drain
    __builtin_amdgcn_sched_barrier(0);
#pragma unroll
    for (int ks = 0; ks < 2; ++ks) {
      const int ko = ks * 32 + (l >> 4) * 8;
      const int rl = l & 15;
      const int sa = (rl & 7) * 8;           // read-side XOR (row mod 8)
      bf16x8 af[4], bfr[4];
#pragma unroll
      for (int m = 0; m < 4; ++m) af[m]  = *(const bf16x8*)&As[cur][(wm + m * 16 + rl) * 64 + (ko ^ sa)];
#pragma unroll
      for (int n = 0; n < 4; ++n) bfr[n] = *(const bf16x8*)&Bs[cur][(wn + n * 16 + rl) * 64 + (ko ^ sa)];
      // SWAPPED: D regs walk Bt-row (N), D lane&15 = A-row (M)
#pragma unroll
      for (int m = 0; m < 4; ++m)
#pragma unroll
        for (int n = 0; n < 4; ++n)
          acc[m][n] = __builtin_amdgcn_mfma_f32_16x16x32_bf16(bfr[n], af[m], acc[m][n], 0, 0, 0);
    }
    __builtin_amdgcn_sched_barrier(0);
    __builtin_amdgcn_s_barrier();            // all waves done reading buf[cur]
    __builtin_amdgcn_sched_barrier(0);
    cur ^= 1;
  }

  // epilogue: lane owns one M row per m-frag; regs = 4 consecutive N
  const int li = l & 15, g4 = (l >> 4) * 4;
  float4 bv[4];
#pragma unroll
  for (int n = 0; n < 4; ++n)
    bv[n] = *(const float4*)&bias[tn * 128 + wn + n * 16 + g4];
#pragma unroll
  for (int m = 0; m < 4; ++m) {
    const int row = (int)arow0 + wm + m * 16 + li;
    // magic div by 49 (exact for row < 409200)
    const int b = (int)(((unsigned long long)(unsigned)row * 342393ull) >> 24);
    const int tok = row - b * 49;
#pragma unroll
    for (int n = 0; n < 4; ++n) {
      float v0 = acc[m][n][0] + bv[n].x;
      float v1 = acc[m][n][1] + bv[n].y;
      float v2 = acc[m][n][2] + bv[n].z;
      float v3 = acc[m][n][3] + bv[n].w;
      const int col = (int)brow0 + wn + n * 16 + g4;
      if (OUT_SLICE) {
        const int t = (col >= 768) ? 2 : ((col >= 384) ? 1 : 0);
        const int rem = col - t * 384;
        const int hh = rem >> 5, d = rem & 31;
        const long dst = (((long)b * NHEAD + hh) * 3 + t) * SLICE + tok * 32 + d;
        u32x2 pk;
        pk[0] = (u32)f2bf(v0) | ((u32)f2bf(v1) << 16);
        pk[1] = (u32)f2bf(v2) | ((u32)f2bf(v3) << 16);
        *(u32x2*)((u16*)C + dst) = pk;
      } else {
        float4 pk; pk.x = v0; pk.y = v1; pk.z = v2; pk.w = v3;
        *(float4*)((float*)C + (long)row * ldc + col) = pk;
      }
    }
  }
}

// ---- MFMA attention (r15 exact — best measured config): slice-major Q/K/V,
//      per-wave V^T LDS staging, mask staged to LDS via gld_lds, one barrier. ----
__global__ __launch_bounds__(256, 4)
void k_attn(const u16* __restrict__ qkv, u16* __restrict__ ob,
            const u32* __restrict__ mpk, const u32* __restrict__ rbp)
{
  __shared__ alignas(16) u16 Vt[4][32 * 64];   // 16KB
  __shared__ alignas(16) u32 mp[1536];         // 5488B used + overflow pad
  const int tid = threadIdx.x;
  const int w = tid >> 6, l = tid & 63;        // w = 0..3
  const int g = l >> 4, li = l & 15;
  const int id = blockIdx.x;
  const int logical = (id & 7) * ((int)gridDim.x >> 3) + (id >> 3);
  const int bl = logical / 3, hg = logical - bl * 3;
  const int h = hg * 4 + w;                    // 12 heads = 3 groups x 4 waves
  const long rowbase = (long)bl * NTOK;
  const float scale = 0.17677669529663687f;

  const long sb = ((long)bl * NHEAD + h) * 3 * SLICE;
  const u16* qs = qkv + sb;
  const u16* ks = qs + SLICE;
  const u16* vs = qs + 2 * SLICE;

  // ---- hoisted K frags + first Q frag (contiguous 1KB per inst) ----
  bf16x8 kf[4];
#pragma unroll
  for (int jm = 0; jm < 4; ++jm) {
    int rj = jm * 16 + li; if (rj >= NTOK) rj = NTOK - 1;
    kf[jm] = *(const bf16x8*)(ks + rj * 32 + g * 8);
  }
  bf16x8 qfc = *(const bf16x8*)(qs + li * 32 + g * 8);   // in=0 rows < 16

  // ---- stage V^T (per-wave), zero-fill j>=49, swizzle col ^= (row&7)<<3 ----
  u16* vt = Vt[w];
  {
    const int jj = l >> 2;
    const int d0 = (l & 3) * 8;
#pragma unroll
    for (int it = 0; it < 4; ++it) {
      int j = it * 16 + jj;
      bf16x8 vv = {0, 0, 0, 0, 0, 0, 0, 0};
      if (j < NTOK)
        vv = *(const bf16x8*)(vs + j * 32 + d0);
#pragma unroll
      for (int t = 0; t < 8; ++t)
        vt[(d0 + t) * 64 + (j ^ (t << 3))] = (u16)vv[t];
    }
  }
  // ---- stage packed mask via wave-uniform gld_lds (5488B) ----
  {
    const u32* mpkb = mpk + (long)bl * (NTOK * MPROW);
    for (int base = w * 1024; base < NTOK * MPROW * 4; base += 4096) {
      int soff = base + l * 16;
      if (soff > NTOK * MPROW * 4 - 16) soff = NTOK * MPROW * 4 - 16;
      gld_lds16((const u16*)((const char*)mpkb + soff), (u16*)((char*)mp + base));
    }
  }
  __syncthreads();

  const int sw = (li & 7) << 3;
  const f32x4 z = {0.f, 0.f, 0.f, 0.f};
  f32x4 oacc[4][2];
#pragma unroll
  for (int im = 0; im < 4; ++im)
#pragma unroll
    for (int dn = 0; dn < 2; ++dn) oacc[im][dn] = z;

  // ---- per-i-block: QK -> (prefetch next Q) -> softmax -> PV ----
#pragma unroll
  for (int in = 0; in < 4; ++in) {
    __builtin_amdgcn_s_setprio(1);
    f32x4 s[4];
#pragma unroll
    for (int jm = 0; jm < 4; ++jm)
      s[jm] = __builtin_amdgcn_mfma_f32_16x16x32_bf16(kf[jm], qfc, z, 0, 0, 0);
    __builtin_amdgcn_s_setprio(0);

    bf16x8 qfn = qfc;
    if (in < 3) {
      int ri = (in + 1) * 16 + li; if (ri >= NTOK) ri = NTOK - 1;
      qfn = *(const bf16x8*)(qs + ri * 32 + g * 8);
    }

    const int i = 16 * in + li;
    const int ic = i < NTOK ? i : NTOK - 1;
#pragma unroll
    for (int jm = 0; jm < 4; ++jm) {
      int p0 = 8 * jm + 2 * g; if (p0 > 24) p0 = 24;
      const u32* bp = rbp + (h * NTOK + ic) * 26 + p0;
      u32 b0w = bp[0], b1w = bp[1];
      u32 m0w = mp[ic * MPROW + p0], m1w = mp[ic * MPROW + p0 + 1];
      s[jm][0] = s[jm][0] * scale + blo(b0w) + blo(m0w);
      s[jm][1] = s[jm][1] * scale + bhi(b0w) + bhi(m0w);
      s[jm][2] = s[jm][2] * scale + blo(b1w) + blo(m1w);
      s[jm][3] = s[jm][3] * scale + bhi(b1w) + bhi(m1w);
    }

    float mx = -3.0e38f;
#pragma unroll
    for (int jm = 0; jm < 4; ++jm)
#pragma unroll
      for (int rr = 0; rr < 4; ++rr) mx = fmaxf(mx, s[jm][rr]);
    mx = fmaxf(mx, __shfl_xor(mx, 16));
    mx = fmaxf(mx, __shfl_xor(mx, 32));
    float sum = 0.f;
#pragma unroll
    for (int jm = 0; jm < 4; ++jm) {
      const int j0 = 16 * jm + 4 * g;
#pragma unroll
      for (int rr = 0; rr < 4; ++rr) {
        float p = (j0 + rr < NTOK) ? __expf(s[jm][rr] - mx) : 0.f;
        s[jm][rr] = p; sum += p;
      }
    }
    sum += __shfl_xor(sum, 16);
    sum += __shfl_xor(sum, 32);
    const float inv = (i < NTOK) ? (1.f / sum) : 0.f;

    __builtin_amdgcn_s_setprio(1);
#pragma unroll
    for (int ks2 = 0; ks2 < 2; ++ks2) {
      union { u32 ww[4]; bf16x8 v8; } pa;
      pa.ww[0] = cvtpk2(s[2 * ks2][0] * inv, s[2 * ks2][1] * inv);
      pa.ww[1] = cvtpk2(s[2 * ks2][2] * inv, s[2 * ks2][3] * inv);
      pa.ww[2] = cvtpk2(s[2 * ks2 + 1][0] * inv, s[2 * ks2 + 1][1] * inv);
      pa.ww[3] = cvtpk2(s[2 * ks2 + 1][2] * inv, s[2 * ks2 + 1][3] * inv);
#pragma unroll
      for (int dn = 0; dn < 2; ++dn) {
        union { bf16x4 hh[2]; bf16x8 v8; } vfr;
        const u16* vrow = &vt[(16 * dn + li) * 64];
        vfr.hh[0] = *(const bf16x4*)&vrow[(32 * ks2 + 4 * g) ^ sw];
        vfr.hh[1] = *(const bf16x4*)&vrow[(32 * ks2 + 16 + 4 * g) ^ sw];
        oacc[in][dn] = __builtin_amdgcn_mfma_f32_16x16x32_bf16(pa.v8, vfr.v8, oacc[in][dn], 0, 0, 0);
      }
    }
    __builtin_amdgcn_s_setprio(0);
    qfc = qfn;
  }

  // ---- store O into ob (row-major Mc x 384) ----
#pragma unroll
  for (int im = 0; im < 4; ++im) {
#pragma unroll
    for (int rr = 0; rr < 4; ++rr) {
      const int i = 16 * im + 4 * g + rr;
      if (i < NTOK) {
        u16* orow = ob + (rowbase + i) * CDIM + h * 32;
#pragma unroll
        for (int dn = 0; dn < 2; ++dn)
          orow[16 * dn + li] = f2bf(oacc[im][dn][rr]);
      }
    }
  }
}

// ---------------- host ----------------
extern "C" void kernel_launch(void* const* d_in, const int* in_sizes, int n_in,
                              void* d_out, int out_size, void* d_ws, size_t ws_size,
                              hipStream_t stream)
{
  const float* x      = (const float*)d_in[0];
  const float* mask   = (const float*)d_in[1];
  const float* qkv_w  = (const float*)d_in[2];
  const float* qkv_b  = (const float*)d_in[3];
  const float* proj_w = (const float*)d_in[4];
  const float* proj_b = (const float*)d_in[5];
  const float* btab   = (const float*)d_in[6];
  const int*   ridx   = (const int*)d_in[7];
  float* out = (float*)d_out;

  const size_t fixed = (size_t)QKVN * CDIM * 2 + (size_t)CDIM * CDIM * 2
                     + (size_t)NHEAD * NTOK * 26 * 4
                     + (size_t)NWIN * NTOK * MPROW * 4 + 1024;
  auto need = [&](int bc) -> size_t {
    return (size_t)bc * NTOK * QKVN * 2      // qkvbuf (slice-major bf16)
         + (size_t)bc * NTOK * CDIM * 2      // xb (bf16 x, then O)
         + fixed;
  };
  int BC = NWIN;
  while (BC > 128 && need(BC) > ws_size) BC >>= 1;

  char* p = (char*)d_ws;
  u16* qkvbuf = (u16*)p;  p += (size_t)BC * NTOK * QKVN * 2;
  u16* xb     = (u16*)p;  p += (size_t)BC * NTOK * CDIM * 2;
  u16* wq     = (u16*)p;  p += (size_t)QKVN * CDIM * 2;
  u16* wp     = (u16*)p;  p += (size_t)CDIM * CDIM * 2;
  u32* rbp    = (u32*)p;  p += (size_t)NHEAD * NTOK * 26 * 4;
  u32* mpk    = (u32*)p;

  k_prep<<<512, 256, 0, stream>>>(qkv_w, proj_w, btab, ridx, mask, wq, wp, rbp, mpk);

  const int nc = NWIN / BC;
  const int Mc = BC * NTOK;
  for (int c = 0; c < nc; ++c) {
    const float* xc = x + (size_t)c * Mc * CDIM;
    k_convx<<<2048, 256, 0, stream>>>(xc, xb, (long)Mc * CDIM / 8);
    k_gemm<true><<<(Mc / 128) * 9, 256, 0, stream>>>(
        xb, CDIM, wq, qkv_b, (void*)qkvbuf, QKVN, CDIM, 9);
    k_attn<<<BC * 3, 256, 0, stream>>>(
        qkvbuf, xb, mpk + (size_t)c * BC * NTOK * MPROW, rbp);
    k_gemm<false><<<(Mc / 128) * 3, 256, 0, stream>>>(
        xb, CDIM, wp, proj_b, (void*)(out + (size_t)c * Mc * CDIM), CDIM, CDIM, 3);
  }
}

// Round 19
// 684.323 us; speedup vs baseline: 1.1223x; 1.1223x over previous
//
#include <hip/hip_runtime.h>
#include <hip/hip_bf16.h>

#define NWIN   4096
#define NTOK   49
#define CDIM   384
#define NHEAD  12
#define QKVN   1152
#define SLICE  1568            // 49*32 elems per (win,head,tensor) slice
#define MPROW  28              // packed-mask row stride (u32), 112B

typedef __attribute__((ext_vector_type(8))) short bf16x8;
typedef __attribute__((ext_vector_type(4))) short bf16x4;
typedef __attribute__((ext_vector_type(4))) float f32x4;
typedef __attribute__((ext_vector_type(2))) unsigned int u32x2;
typedef unsigned int u32;
typedef unsigned short u16;

static __device__ __forceinline__ u16 f2bf(float f) {
  union { float f; u32 u; } w; w.f = f;
  u32 r = w.u + 0x7fffu + ((w.u >> 16) & 1u);
  return (u16)(r >> 16);
}
static __device__ __forceinline__ float blo(u32 v) {
  union { u32 u; float f; } w; w.u = v << 16; return w.f;
}
static __device__ __forceinline__ float bhi(u32 v) {
  union { u32 u; float f; } w; w.u = v & 0xffff0000u; return w.f;
}
static __device__ __forceinline__ u32 cvtpk2(float lo, float hi) {
  u32 r; asm("v_cvt_pk_bf16_f32 %0, %1, %2" : "=v"(r) : "v"(lo), "v"(hi));
  return r;
}
static __device__ __forceinline__ void gld_lds16(const u16* g, u16* l) {
  __builtin_amdgcn_global_load_lds((const __attribute__((address_space(1))) u32*)g,
                                   (__attribute__((address_space(3))) u32*)l, 16, 0, 0);
}

// ---- prep: weights -> bf16, packed rel_bias gather, packed bf16 mask ----
__global__ void k_prep(const float* __restrict__ qkv_w, const float* __restrict__ proj_w,
                       const float* __restrict__ btab, const int* __restrict__ ridx,
                       const float* __restrict__ mask,
                       u16* __restrict__ wq, u16* __restrict__ wp, u32* __restrict__ rbp,
                       u32* __restrict__ mpk)
{
  const int n1 = QKVN * CDIM;
  const int n2 = CDIM * CDIM;
  const int n3 = NHEAD * NTOK * 26;
  const int n4 = NWIN * NTOK * MPROW;
  for (int i = blockIdx.x * blockDim.x + threadIdx.x; i < n1 + n2 + n3 + n4;
       i += gridDim.x * blockDim.x) {
    if (i < n1) {
      wq[i] = f2bf(qkv_w[i]);
    } else if (i < n1 + n2) {
      wp[i - n1] = f2bf(proj_w[i - n1]);
    } else if (i < n1 + n2 + n3) {
      int t = i - n1 - n2;
      int h = t / (NTOK * 26); int rem = t % (NTOK * 26);
      int r = rem / 26, p = rem % 26;
      float lo = 0.f, hi = 0.f;
      if (p < 25) {
        lo = btab[ridx[r * NTOK + 2 * p] * NHEAD + h];
        if (2 * p + 1 < NTOK) hi = btab[ridx[r * NTOK + 2 * p + 1] * NHEAD + h];
      }
      rbp[(h * NTOK + r) * 26 + p] = (u32)f2bf(lo) | ((u32)f2bf(hi) << 16);
    } else {
      int t2 = i - n1 - n2 - n3;          // [0, NWIN*49*28)
      int wi = t2 / MPROW, p = t2 - wi * MPROW;
      u32 v = 0;
      if (p < 25) {
        const float* mrow = mask + (long)wi * NTOK;   // wi = win*49 + row
        float lo = mrow[2 * p];
        float hi = (2 * p + 1 < NTOK) ? mrow[2 * p + 1] : 0.f;
        v = (u32)f2bf(lo) | ((u32)f2bf(hi) << 16);
      }
      mpk[t2] = v;
    }
  }
}

// ---------------- x fp32 -> bf16 ----------------
__global__ void k_convx(const float* __restrict__ x, u16* __restrict__ xb, long n8)
{
  long i = (long)blockIdx.x * blockDim.x + threadIdx.x;
  long stride = (long)gridDim.x * blockDim.x;
  for (; i < n8; i += stride) {
    const float4* p = (const float4*)x + i * 2;
    float4 a = p[0], b = p[1];
    u32 w0 = (u32)f2bf(a.x) | ((u32)f2bf(a.y) << 16);
    u32 w1 = (u32)f2bf(a.z) | ((u32)f2bf(a.w) << 16);
    u32 w2 = (u32)f2bf(b.x) | ((u32)f2bf(b.y) << 16);
    u32 w3 = (u32)f2bf(b.z) | ((u32)f2bf(b.w) << 16);
    uint4 v; v.x = w0; v.y = w1; v.z = w2; v.w = w3;
    ((uint4*)xb)[i] = v;
  }
}

// ---- 128x128 GEMM (r15 exact — best measured): T2 swizzle via pre-swizzled
//      source + XCD-chunked blocks, single-buffered, (256,4).
//      OUT_SLICE: write bf16 slice-major qkvbuf; else fp32 row-major + bias. ----
template<bool OUT_SLICE>
__global__ __launch_bounds__(256, 4)
void k_gemm(const u16* __restrict__ A, int lda,
            const u16* __restrict__ Bt, const float* __restrict__ bias,
            void* __restrict__ C, int ldc, int K, int tiles_n)
{
  __shared__ alignas(16) u16 As[128 * 64];
  __shared__ alignas(16) u16 Bs[128 * 64];
  const int tid = threadIdx.x;
  const int w = tid >> 6, l = tid & 63;

  // bijective XCD-chunk swizzle (m204)
  const int nwg = (int)gridDim.x;
  const int xcd = (int)blockIdx.x & 7, idx8 = (int)blockIdx.x >> 3;
  const int q8 = nwg >> 3, r8w = nwg & 7;
  const int lid = (xcd < r8w ? xcd * (q8 + 1) : r8w * (q8 + 1) + (xcd - r8w) * q8) + idx8;

  const int tm = lid / tiles_n, tn = lid % tiles_n;
  const int wm = (w >> 1) * 64, wn = (w & 1) * 64;
  const long arow0 = (long)tm * 128;
  const long brow0 = (long)tn * 128;
  const int r8 = l >> 3;                      // row within 8-row staging chunk
  const int c8 = ((l & 7) ^ r8) * 8;          // PRE-SWIZZLED source col (elems)

  f32x4 acc[4][4];
  const f32x4 z = {0.f, 0.f, 0.f, 0.f};
#pragma unroll
  for (int m = 0; m < 4; ++m)
#pragma unroll
    for (int n = 0; n < 4; ++n) acc[m][n] = z;

  for (int kk = 0; kk < K; kk += 64) {
    __syncthreads();
#pragma unroll
    for (int q = 0; q < 4; ++q) {
      int ra = w * 32 + q * 8;
      gld_lds16(A  + (arow0 + ra + r8) * (long)lda + kk + c8, &As[ra * 64]);
      gld_lds16(Bt + (brow0 + ra + r8) * (long)K   + kk + c8, &Bs[ra * 64]);
    }
    __syncthreads();
#pragma unroll
    for (int ks = 0; ks < 2; ++ks) {
      const int ko = ks * 32 + (l >> 4) * 8;
      const int rl = l & 15;
      const int sa = (rl & 7) * 8;            // read-side XOR (row mod 8)
      bf16x8 af[4], bfr[4];
#pragma unroll
      for (int m = 0; m < 4; ++m) af[m]  = *(const bf16x8*)&As[(wm + m * 16 + rl) * 64 + (ko ^ sa)];
#pragma unroll
      for (int n = 0; n < 4; ++n) bfr[n] = *(const bf16x8*)&Bs[(wn + n * 16 + rl) * 64 + (ko ^ sa)];
      // SWAPPED: D regs walk Bt-row (N), D lane&15 = A-row (M)
#pragma unroll
      for (int m = 0; m < 4; ++m)
#pragma unroll
        for (int n = 0; n < 4; ++n)
          acc[m][n] = __builtin_amdgcn_mfma_f32_16x16x32_bf16(bfr[n], af[m], acc[m][n], 0, 0, 0);
    }
  }

  // epilogue: lane owns one M row per m-frag; regs = 4 consecutive N
  const int li = l & 15, g4 = (l >> 4) * 4;
  float4 bv[4];
#pragma unroll
  for (int n = 0; n < 4; ++n)
    bv[n] = *(const float4*)&bias[tn * 128 + wn + n * 16 + g4];
#pragma unroll
  for (int m = 0; m < 4; ++m) {
    const int row = (int)arow0 + wm + m * 16 + li;
    // magic div by 49 (exact for row < 409200)
    const int b = (int)(((unsigned long long)(unsigned)row * 342393ull) >> 24);
    const int tok = row - b * 49;
#pragma unroll
    for (int n = 0; n < 4; ++n) {
      float v0 = acc[m][n][0] + bv[n].x;
      float v1 = acc[m][n][1] + bv[n].y;
      float v2 = acc[m][n][2] + bv[n].z;
      float v3 = acc[m][n][3] + bv[n].w;
      const int col = (int)brow0 + wn + n * 16 + g4;
      if (OUT_SLICE) {
        const int t = (col >= 768) ? 2 : ((col >= 384) ? 1 : 0);
        const int rem = col - t * 384;
        const int hh = rem >> 5, d = rem & 31;
        const long dst = (((long)b * NHEAD + hh) * 3 + t) * SLICE + tok * 32 + d;
        u32x2 pk;
        pk[0] = (u32)f2bf(v0) | ((u32)f2bf(v1) << 16);
        pk[1] = (u32)f2bf(v2) | ((u32)f2bf(v3) << 16);
        *(u32x2*)((u16*)C + dst) = pk;
      } else {
        float4 pk; pk.x = v0; pk.y = v1; pk.z = v2; pk.w = v3;
        *(float4*)((float*)C + (long)row * ldc + col) = pk;
      }
    }
  }
}

// ---- MFMA attention (r15 exact — best measured): slice-major Q/K/V,
//      per-wave V^T LDS staging, mask staged to LDS via gld_lds, one barrier. ----
__global__ __launch_bounds__(256, 4)
void k_attn(const u16* __restrict__ qkv, u16* __restrict__ ob,
            const u32* __restrict__ mpk, const u32* __restrict__ rbp)
{
  __shared__ alignas(16) u16 Vt[4][32 * 64];   // 16KB
  __shared__ alignas(16) u32 mp[1536];         // 5488B used + overflow pad
  const int tid = threadIdx.x;
  const int w = tid >> 6, l = tid & 63;        // w = 0..3
  const int g = l >> 4, li = l & 15;
  const int id = blockIdx.x;
  const int logical = (id & 7) * ((int)gridDim.x >> 3) + (id >> 3);
  const int bl = logical / 3, hg = logical - bl * 3;
  const int h = hg * 4 + w;                    // 12 heads = 3 groups x 4 waves
  const long rowbase = (long)bl * NTOK;
  const float scale = 0.17677669529663687f;

  const long sb = ((long)bl * NHEAD + h) * 3 * SLICE;
  const u16* qs = qkv + sb;
  const u16* ks = qs + SLICE;
  const u16* vs = qs + 2 * SLICE;

  // ---- hoisted K frags + first Q frag (contiguous 1KB per inst) ----
  bf16x8 kf[4];
#pragma unroll
  for (int jm = 0; jm < 4; ++jm) {
    int rj = jm * 16 + li; if (rj >= NTOK) rj = NTOK - 1;
    kf[jm] = *(const bf16x8*)(ks + rj * 32 + g * 8);
  }
  bf16x8 qfc = *(const bf16x8*)(qs + li * 32 + g * 8);   // in=0 rows < 16

  // ---- stage V^T (per-wave), zero-fill j>=49, swizzle col ^= (row&7)<<3 ----
  u16* vt = Vt[w];
  {
    const int jj = l >> 2;
    const int d0 = (l & 3) * 8;
#pragma unroll
    for (int it = 0; it < 4; ++it) {
      int j = it * 16 + jj;
      bf16x8 vv = {0, 0, 0, 0, 0, 0, 0, 0};
      if (j < NTOK)
        vv = *(const bf16x8*)(vs + j * 32 + d0);
#pragma unroll
      for (int t = 0; t < 8; ++t)
        vt[(d0 + t) * 64 + (j ^ (t << 3))] = (u16)vv[t];
    }
  }
  // ---- stage packed mask via wave-uniform gld_lds (5488B) ----
  {
    const u32* mpkb = mpk + (long)bl * (NTOK * MPROW);
    for (int base = w * 1024; base < NTOK * MPROW * 4; base += 4096) {
      int soff = base + l * 16;
      if (soff > NTOK * MPROW * 4 - 16) soff = NTOK * MPROW * 4 - 16;
      gld_lds16((const u16*)((const char*)mpkb + soff), (u16*)((char*)mp + base));
    }
  }
  __syncthreads();

  const int sw = (li & 7) << 3;
  const f32x4 z = {0.f, 0.f, 0.f, 0.f};
  f32x4 oacc[4][2];
#pragma unroll
  for (int im = 0; im < 4; ++im)
#pragma unroll
    for (int dn = 0; dn < 2; ++dn) oacc[im][dn] = z;

  // ---- per-i-block: QK -> (prefetch next Q) -> softmax -> PV ----
#pragma unroll
  for (int in = 0; in < 4; ++in) {
    __builtin_amdgcn_s_setprio(1);
    f32x4 s[4];
#pragma unroll
    for (int jm = 0; jm < 4; ++jm)
      s[jm] = __builtin_amdgcn_mfma_f32_16x16x32_bf16(kf[jm], qfc, z, 0, 0, 0);
    __builtin_amdgcn_s_setprio(0);

    bf16x8 qfn = qfc;
    if (in < 3) {
      int ri = (in + 1) * 16 + li; if (ri >= NTOK) ri = NTOK - 1;
      qfn = *(const bf16x8*)(qs + ri * 32 + g * 8);
    }

    const int i = 16 * in + li;
    const int ic = i < NTOK ? i : NTOK - 1;
#pragma unroll
    for (int jm = 0; jm < 4; ++jm) {
      int p0 = 8 * jm + 2 * g; if (p0 > 24) p0 = 24;
      const u32* bp = rbp + (h * NTOK + ic) * 26 + p0;
      u32 b0w = bp[0], b1w = bp[1];
      u32 m0w = mp[ic * MPROW + p0], m1w = mp[ic * MPROW + p0 + 1];
      s[jm][0] = s[jm][0] * scale + blo(b0w) + blo(m0w);
      s[jm][1] = s[jm][1] * scale + bhi(b0w) + bhi(m0w);
      s[jm][2] = s[jm][2] * scale + blo(b1w) + blo(m1w);
      s[jm][3] = s[jm][3] * scale + bhi(b1w) + bhi(m1w);
    }

    float mx = -3.0e38f;
#pragma unroll
    for (int jm = 0; jm < 4; ++jm)
#pragma unroll
      for (int rr = 0; rr < 4; ++rr) mx = fmaxf(mx, s[jm][rr]);
    mx = fmaxf(mx, __shfl_xor(mx, 16));
    mx = fmaxf(mx, __shfl_xor(mx, 32));
    float sum = 0.f;
#pragma unroll
    for (int jm = 0; jm < 4; ++jm) {
      const int j0 = 16 * jm + 4 * g;
#pragma unroll
      for (int rr = 0; rr < 4; ++rr) {
        float p = (j0 + rr < NTOK) ? __expf(s[jm][rr] - mx) : 0.f;
        s[jm][rr] = p; sum += p;
      }
    }
    sum += __shfl_xor(sum, 16);
    sum += __shfl_xor(sum, 32);
    const float inv = (i < NTOK) ? (1.f / sum) : 0.f;

    __builtin_amdgcn_s_setprio(1);
#pragma unroll
    for (int ks2 = 0; ks2 < 2; ++ks2) {
      union { u32 ww[4]; bf16x8 v8; } pa;
      pa.ww[0] = cvtpk2(s[2 * ks2][0] * inv, s[2 * ks2][1] * inv);
      pa.ww[1] = cvtpk2(s[2 * ks2][2] * inv, s[2 * ks2][3] * inv);
      pa.ww[2] = cvtpk2(s[2 * ks2 + 1][0] * inv, s[2 * ks2 + 1][1] * inv);
      pa.ww[3] = cvtpk2(s[2 * ks2 + 1][2] * inv, s[2 * ks2 + 1][3] * inv);
#pragma unroll
      for (int dn = 0; dn < 2; ++dn) {
        union { bf16x4 hh[2]; bf16x8 v8; } vfr;
        const u16* vrow = &vt[(16 * dn + li) * 64];
        vfr.hh[0] = *(const bf16x4*)&vrow[(32 * ks2 + 4 * g) ^ sw];
        vfr.hh[1] = *(const bf16x4*)&vrow[(32 * ks2 + 16 + 4 * g) ^ sw];
        oacc[in][dn] = __builtin_amdgcn_mfma_f32_16x16x32_bf16(pa.v8, vfr.v8, oacc[in][dn], 0, 0, 0);
      }
    }
    __builtin_amdgcn_s_setprio(0);
    qfc = qfn;
  }

  // ---- store O into ob (row-major Mc x 384) ----
#pragma unroll
  for (int im = 0; im < 4; ++im) {
#pragma unroll
    for (int rr = 0; rr < 4; ++rr) {
      const int i = 16 * im + 4 * g + rr;
      if (i < NTOK) {
        u16* orow = ob + (rowbase + i) * CDIM + h * 32;
#pragma unroll
        for (int dn = 0; dn < 2; ++dn)
          orow[16 * dn + li] = f2bf(oacc[im][dn][rr]);
      }
    }
  }
}

// ---------------- host ----------------
extern "C" void kernel_launch(void* const* d_in, const int* in_sizes, int n_in,
                              void* d_out, int out_size, void* d_ws, size_t ws_size,
                              hipStream_t stream)
{
  const float* x      = (const float*)d_in[0];
  const float* mask   = (const float*)d_in[1];
  const float* qkv_w  = (const float*)d_in[2];
  const float* qkv_b  = (const float*)d_in[3];
  const float* proj_w = (const float*)d_in[4];
  const float* proj_b = (const float*)d_in[5];
  const float* btab   = (const float*)d_in[6];
  const int*   ridx   = (const int*)d_in[7];
  float* out = (float*)d_out;

  const size_t fixed = (size_t)QKVN * CDIM * 2 + (size_t)CDIM * CDIM * 2
                     + (size_t)NHEAD * NTOK * 26 * 4
                     + (size_t)NWIN * NTOK * MPROW * 4 + 1024;
  auto need = [&](int bc) -> size_t {
    return (size_t)bc * NTOK * QKVN * 2      // qkvbuf (slice-major bf16)
         + (size_t)bc * NTOK * CDIM * 2      // xb (bf16 x, then O)
         + fixed;
  };
  int BC = NWIN;
  while (BC > 128 && need(BC) > ws_size) BC >>= 1;

  char* p = (char*)d_ws;
  u16* qkvbuf = (u16*)p;  p += (size_t)BC * NTOK * QKVN * 2;
  u16* xb     = (u16*)p;  p += (size_t)BC * NTOK * CDIM * 2;
  u16* wq     = (u16*)p;  p += (size_t)QKVN * CDIM * 2;
  u16* wp     = (u16*)p;  p += (size_t)CDIM * CDIM * 2;
  u32* rbp    = (u32*)p;  p += (size_t)NHEAD * NTOK * 26 * 4;
  u32* mpk    = (u32*)p;

  k_prep<<<512, 256, 0, stream>>>(qkv_w, proj_w, btab, ridx, mask, wq, wp, rbp, mpk);

  const int nc = NWIN / BC;
  const int Mc = BC * NTOK;
  for (int c = 0; c < nc; ++c) {
    const float* xc = x + (size_t)c * Mc * CDIM;
    k_convx<<<2048, 256, 0, stream>>>(xc, xb, (long)Mc * CDIM / 8);
    k_gemm<true><<<(Mc / 128) * 9, 256, 0, stream>>>(
        xb, CDIM, wq, qkv_b, (void*)qkvbuf, QKVN, CDIM, 9);
    k_attn<<<BC * 3, 256, 0, stream>>>(
        qkvbuf, xb, mpk + (size_t)c * BC * NTOK * MPROW, rbp);
    k_gemm<false><<<(Mc / 128) * 3, 256, 0, stream>>>(
        xb, CDIM, wp, proj_b, (void*)(out + (size_t)c * Mc * CDIM), CDIM, CDIM, 3);
  }
}